// Round 8
// baseline (148.802 us; speedup 1.0000x reference)
//
#include <hip/hip_runtime.h>
#include <stdint.h>

typedef unsigned short u16;
typedef __attribute__((ext_vector_type(8))) short bf16x8;   // 8 bf16 in 4 VGPRs
typedef __attribute__((ext_vector_type(4))) float floatx4;

#define MFMA16(a, b, c) __builtin_amdgcn_mfma_f32_16x16x32_bf16(a, b, c, 0, 0, 0)
#define MEMFENCE asm volatile("" ::: "memory")

#if __has_builtin(__builtin_amdgcn_exp2f)
#define EXP2(x) __builtin_amdgcn_exp2f(x)
#else
#define EXP2(x) __expf(0.6931471805599453f * (x))
#endif

__device__ __forceinline__ u16 f2bf(float f) {   // round-to-nearest-even
  unsigned u = __builtin_bit_cast(unsigned, f);
  return (u16)((u + 0x7FFFu + ((u >> 16) & 1u)) >> 16);
}
__device__ __forceinline__ float bf2f(u16 v) {
  return __builtin_bit_cast(float, (unsigned)v << 16);
}

// pack 2 f32 -> 2 bf16 in one u32 (RNE). No builtin on gfx950 (T12): inline asm.
__device__ __forceinline__ unsigned cvtpk(float lo, float hi) {
  unsigned d;
  asm("v_cvt_pk_bf16_f32 %0, %1, %2" : "=v"(d) : "v"(lo), "v"(hi));
  return d;
}
// gfx950 half-swap primitives (VALU pipe, not DS). Both registers updated:
// P32: a=[a0,a1,b0,b1] b=[a2,a3,b2,b3]; P16: a=[a0,b0,a2,b2] b=[a1,b1,a3,b3]
// (quarters = 16-lane groups).
__device__ __forceinline__ void perm32swap(unsigned& a, unsigned& b) {
  asm("v_permlane32_swap_b32 %0, %1" : "+v"(a), "+v"(b));
}
__device__ __forceinline__ void perm16swap(unsigned& a, unsigned& b) {
  asm("v_permlane16_swap_b32 %0, %1" : "+v"(a), "+v"(b));
}

// async global->LDS, 16B/lane. LDS dest = wave-uniform base + lane*16 (HW).
__device__ __forceinline__ void glds16(void* lds, const void* g) {
  __builtin_amdgcn_global_load_lds((const __attribute__((address_space(1))) void*)g,
                                   (__attribute__((address_space(3))) void*)lds,
                                   16, 0, 0);
}

// ---------------------------------------------------------------- convert
__global__ __launch_bounds__(256) void cvt_all(
    const float* __restrict__ x, const float* __restrict__ w0,
    const float* __restrict__ w1, const float* __restrict__ w2,
    u16* __restrict__ xb, u16* __restrict__ Wb) {
  const int bid = blockIdx.x;
  const float* src;
  u16* dst;
  int i;
  if (bid < 4096) {
    src = x; dst = xb; i = bid * 256 + threadIdx.x;
  } else {
    const int z = (bid - 4096) >> 10;
    src = (z == 0) ? w0 : (z == 1) ? w1 : w2;
    dst = Wb + (size_t)z * (1024 * 1024);
    i = ((bid - 4096) & 1023) * 256 + threadIdx.x;
  }
  float4 f = reinterpret_cast<const float4*>(src)[i];
  ushort4 o;
  o.x = f2bf(f.x); o.y = f2bf(f.y); o.z = f2bf(f.z); o.w = f2bf(f.w);
  reinterpret_cast<ushort4*>(dst)[i] = o;
}

// ---------------------------------------------------------------- QKV GEMM
// (unchanged, proven) C[m,n] = sum_k x[m,k]*W[n,k] + bias[n].
__global__ __launch_bounds__(256, 3) void qkv_gemm(
    const u16* __restrict__ xb, const u16* __restrict__ Wb,
    const float* __restrict__ bq, const float* __restrict__ bk,
    const float* __restrict__ bv,
    u16* __restrict__ Qb, u16* __restrict__ Kb, u16* __restrict__ VTb) {
  __shared__ __attribute__((aligned(16))) u16 smem[2 * 128 * 64];   // 32KB
  u16* As = smem;
  u16* Bs = smem + 128 * 64;

  const int tid = threadIdx.x;
  const int w = tid >> 6, lane = tid & 63;
  const int lo = lane & 15, quad = lane >> 4;
  const int which = blockIdx.z;
  const int m0 = blockIdx.x * 128, n0 = blockIdx.y * 128;

  const u16* W = Wb + (size_t)which * (1024 * 1024);
  const int wm = (w >> 1) * 64, wn = (w & 1) * 64;

  floatx4 acc[4][4];
  for (int i = 0; i < 4; ++i)
    for (int j = 0; j < 4; ++j) acc[i][j] = (floatx4)0.f;

  const int arow = lane >> 3;                 // 0..7 within 8-row segment
  const int aswz = ((lane & 7) ^ arow) * 8;   // swizzled global col chunk

  for (int kt = 0; kt < 16; ++kt) {
    const int k0 = kt * 64;
    for (int j = 0; j < 4; ++j) {
      const int seg = w * 4 + j;              // 16 segs of 8 rows each side
      glds16(As + seg * 512, xb + (size_t)(m0 + seg * 8 + arow) * 1024 + k0 + aswz);
      glds16(Bs + seg * 512, W + (size_t)(n0 + seg * 8 + arow) * 1024 + k0 + aswz);
    }
    __syncthreads();
    for (int kk = 0; kk < 2; ++kk) {
      const int swz = ((kk * 4 + quad) ^ (lo & 7)) * 8;
      bf16x8 af[4], bfr[4];
      for (int it = 0; it < 4; ++it)
        af[it] = *reinterpret_cast<const bf16x8*>(As + (wm + it * 16 + lo) * 64 + swz);
      for (int jt = 0; jt < 4; ++jt)
        bfr[jt] = *reinterpret_cast<const bf16x8*>(Bs + (wn + jt * 16 + lo) * 64 + swz);
      for (int it = 0; it < 4; ++it)
        for (int jt = 0; jt < 4; ++jt)
          acc[it][jt] = MFMA16(af[it], bfr[jt], acc[it][jt]);
    }
    __syncthreads();
  }

  const float* bias = (which == 0) ? bq : (which == 1) ? bk : bv;
  float bb[4];
  for (int jt = 0; jt < 4; ++jt) bb[jt] = bias[n0 + wn + jt * 16 + lo];
  const int b = m0 >> 11;

  if (which < 2) {
    // per-wave 16x64 transpose tiles (pad->72, swizzled)
    const float scl = (which == 0) ? 0.36067376022224085f : 1.0f;  // 0.25*log2e
    u16* Tw = smem + w * (16 * 72);
    const int hblk = (n0 + wn) >> 6;
    u16* dst = ((which == 0) ? Qb : Kb) +
               ((size_t)(b * 16 + hblk) * 2048 + ((m0 & 2047) + wm)) * 64;
    for (int it = 0; it < 4; ++it) {
      for (int jt = 0; jt < 4; ++jt)
        for (int r = 0; r < 4; ++r) {
          const int m = quad * 4 + r, col = jt * 16 + lo;
          Tw[m * 72 + (((col >> 3) ^ (m & 7)) * 8) + (col & 7)] =
              f2bf((acc[it][jt][r] + bb[jt]) * scl);
        }
      MEMFENCE;   // scalar u16 writes -> vector reads, same wave: keep order
      for (int rd = 0; rd < 2; ++rd) {   // per-wave in-order DS: no barrier
        const int sr = rd * 8 + (lane >> 3), d8 = lane & 7;
        bf16x8 v = *reinterpret_cast<const bf16x8*>(Tw + sr * 72 + ((d8 ^ (sr & 7)) * 8));
        *reinterpret_cast<bf16x8*>(dst + (size_t)(it * 16 + sr) * 64 + d8 * 8) = v;
      }
      MEMFENCE;   // vector reads done before next it overwrites Tw
    }
  } else {
    // V^T: block transpose [128 n][64 m] (pad->72) in two m-passes.
    for (int pass = 0; pass < 2; ++pass) {
      if ((wm >> 6) == pass) {
        for (int it = 0; it < 4; ++it)
          for (int jt = 0; jt < 4; ++jt)
            for (int r = 0; r < 4; ++r) {
              const int n = wn + jt * 16 + lo;
              const int m = it * 16 + quad * 4 + r;   // local 0..63
              smem[n * 72 + (((m >> 3) ^ (n & 7)) * 8) + (m & 7)] =
                  f2bf(acc[it][jt][r] + bb[jt]);
            }
      }
      __syncthreads();
      for (int rd = 0; rd < 4; ++rd) {
        const int n = (tid >> 3) + rd * 32, m8 = tid & 7;
        bf16x8 v = *reinterpret_cast<const bf16x8*>(smem + n * 72 + ((m8 ^ (n & 7)) * 8));
        const int ng = n0 + n, h = ng >> 6, d = ng & 63;
        const int s = (m0 & 2047) + pass * 64 + m8 * 8;
        *reinterpret_cast<bf16x8*>(VTb + ((size_t)(b * 16 + h) * 64 + d) * 2048 + s) = v;
      }
      __syncthreads();
    }
  }
}

// ---------------------------------------------------------------- attention
// R8 = R7 retry with the suspect surface removed. R7 failed despite a full
// logic audit; triangulation (R1 passed: 2-wave+2-qset+shared-ka/va+Pt-LDS;
// R6 passed: 4-wave+1-qset+T12) narrows the fault to the s-inner PV building
// pb[2] around 8 in-place "+v" asm chains under the (128,3) VGPR cap.
// R8: PV is s-OUTER, each (s,kk) body is R6's proven code VERBATIM (scalar
// pb, own va reads -- V read once per qset, trading half the V-sharing for
// proven shape); bounds relaxed to R1-proven (128,2) (no regalloc pressure);
// explicit unroll pragmas everywhere (rule #20). DS/64q-tile: 80KB(R6)->64KB.
// LDS 32KB -> 5 blocks/CU = 10 waves/CU, 5 barrier groups.
__global__ __launch_bounds__(128, 2) void attn(
    const u16* __restrict__ Qb, const u16* __restrict__ Kb,
    const u16* __restrict__ VTb, float* __restrict__ out) {
  __shared__ __attribute__((aligned(16))) u16 Ks[2][64 * 64];   // [key][d] swz
  __shared__ __attribute__((aligned(16))) u16 Vs[2][64 * 64];   // [d][key] swz

  const int L = blockIdx.x;                 // 32 fix + 1024 main
  if (L < 32) {
    // ---- fix2047: row 2047 fully masked -> uniform softmax = mean_s V ----
    const int bh = L;
    const u16* Vh = VTb + (size_t)bh * (64 * 2048);
    const int t = threadIdx.x;
    const int d = t >> 1, jj = t & 1;
    float s = 0.f;
    const u16* row = Vh + (size_t)d * 2048 + jj * 1024;
    for (int i = 0; i < 128; ++i) {
      bf16x8 v = *reinterpret_cast<const bf16x8*>(row + i * 8);
      for (int e = 0; e < 8; ++e) s += bf2f((u16)v[e]);
    }
    s += __shfl_xor(s, 1);
    if (jj == 0) {
      const int b = bh >> 4, h = bh & 15;
      out[((size_t)(b * 2048 + 2047)) * 1024 + h * 64 + d] = s * (1.f / 2048.f);
    }
    return;
  }

  const int M = L - 32;                     // 1024 main blocks
  const int bh = M & 31;                    // bh%8 = L%8 -> 4 bh per XCD (L2)
  const int j = M >> 5;                     // 0..31
  const int g = j >> 3, r = j & 7;
  const int qi = (g == 0) ? r : (g == 1) ? 15 - r : (g == 2) ? 16 + r : 31 - r;
  const int kstart = qi;                    // diagonal 64-key tile

  const int tid = threadIdx.x, w = tid >> 6, lane = tid & 63;
  const int lo = lane & 15, quad = lane >> 4;

  const u16* Qh = Qb + (size_t)bh * (2048 * 64);
  const u16* Kh = Kb + (size_t)bh * (2048 * 64);
  const u16* Vh = VTb + (size_t)bh * (64 * 2048);

  int qrow[2];
  bf16x8 qf[2][2];
#pragma unroll
  for (int s = 0; s < 2; ++s) {
    qrow[s] = qi * 64 + w * 32 + s * 16 + lo;
    qf[s][0] = *reinterpret_cast<const bf16x8*>(Qh + (size_t)qrow[s] * 64 + quad * 8);
    qf[s][1] = *reinterpret_cast<const bf16x8*>(Qh + (size_t)qrow[s] * 64 + 32 + quad * 8);
  }

  float lrun[2] = {0.f, 0.f};
  floatx4 acc[2][4];
#pragma unroll
  for (int s = 0; s < 2; ++s)
#pragma unroll
    for (int dt = 0; dt < 4; ++dt) acc[s][dt] = (floatx4)0.f;

  const int srow8 = lane >> 3, sblk = lane & 7;
  const int sswz = (sblk ^ srow8) * 8;          // staging XOR swizzle

#pragma unroll
  for (int jj = 0; jj < 4; ++jj) {   // prologue: stage tile kstart into buf 0
    const int b8 = (w * 4 + jj) * 8;
    glds16(&Ks[0][b8 * 64], Kh + (size_t)(kstart * 64 + b8 + srow8) * 64 + sswz);
    glds16(&Vs[0][b8 * 64], Vh + (size_t)(b8 + srow8) * 2048 + kstart * 64 + sswz);
  }
  __syncthreads();

  for (int kt = kstart; kt < 32; ++kt) {
    const int cur = (kt - kstart) & 1, nxt = cur ^ 1;
    if (kt < 31)   // prefetch next tile before compute
#pragma unroll
      for (int jj = 0; jj < 4; ++jj) {
        const int b8 = (w * 4 + jj) * 8;
        glds16(&Ks[nxt][b8 * 64], Kh + (size_t)((kt + 1) * 64 + b8 + srow8) * 64 + sswz);
        glds16(&Vs[nxt][b8 * 64], Vh + (size_t)(b8 + srow8) * 2048 + (kt + 1) * 64 + sswz);
      }
    const u16* ksb = Ks[cur];
    const u16* vsb = Vs[cur];

    const bool maskp = (kt == kstart);   // only the diagonal tile masks

    // QK^T: K fragments read once, used for both qsets (R1-proven pattern)
    floatx4 sc[2][4];
#pragma unroll
    for (int s = 0; s < 2; ++s)
#pragma unroll
      for (int t = 0; t < 4; ++t) sc[s][t] = (floatx4)0.f;
#pragma unroll
    for (int kk = 0; kk < 2; ++kk) {
      const int swz = ((kk * 4 + quad) ^ (lo & 7)) * 8;
#pragma unroll
      for (int t = 0; t < 4; ++t) {
        bf16x8 ka = *reinterpret_cast<const bf16x8*>(ksb + (t * 16 + lo) * 64 + swz);
        sc[0][t] = MFMA16(ka, qf[0][kk], sc[0][t]);
        sc[1][t] = MFMA16(ka, qf[1][kk], sc[1][t]);
      }
    }

    // exp + pack per qset: pkA[s][t]=[p0,p1], pkB[s][t]=[p2,p3]
    unsigned pkA[2][4], pkB[2][4];
#pragma unroll
    for (int s = 0; s < 2; ++s)
#pragma unroll
      for (int t = 0; t < 4; ++t) {
        float p0 = EXP2(sc[s][t][0]), p1 = EXP2(sc[s][t][1]);
        float p2 = EXP2(sc[s][t][2]), p3 = EXP2(sc[s][t][3]);
        if (maskp) {   // keep key > q (faithful buggy mask)
          const int key = kt * 64 + t * 16 + quad * 4;
          p0 = (key + 0 > qrow[s]) ? p0 : 0.f;
          p1 = (key + 1 > qrow[s]) ? p1 : 0.f;
          p2 = (key + 2 > qrow[s]) ? p2 : 0.f;
          p3 = (key + 3 > qrow[s]) ? p3 : 0.f;
        }
        lrun[s] += (p0 + p1) + (p2 + p3);
        pkA[s][t] = cvtpk(p0, p1);
        pkB[s][t] = cvtpk(p2, p3);
      }

    // PV: s-OUTER, each (s,kk) body is R6's proven code verbatim
#pragma unroll
    for (int s = 0; s < 2; ++s) {
#pragma unroll
      for (int kk = 0; kk < 2; ++kk) {
        unsigned a0 = pkA[s][2 * kk], a1 = pkA[s][2 * kk + 1];
        unsigned b0 = pkB[s][2 * kk], b1 = pkB[s][2 * kk + 1];
        perm32swap(a0, a1); perm16swap(a0, a1);   // a0=PB0, a1=PB2
        perm32swap(b0, b1); perm16swap(b0, b1);   // b0=PB1, b1=PB3
        uint4 pw; pw.x = a0; pw.y = b0; pw.z = a1; pw.w = b1;
        const bf16x8 pb = __builtin_bit_cast(bf16x8, pw);
        const int pswz = ((kk * 4 + quad) ^ (lo & 7)) * 8;
#pragma unroll
        for (int dt = 0; dt < 4; ++dt) {
          bf16x8 va = *reinterpret_cast<const bf16x8*>(vsb + (dt * 16 + lo) * 64 + pswz);
          acc[s][dt] = MFMA16(va, pb, acc[s][dt]);
        }
      }
    }
    __syncthreads();   // staging of nxt complete + both waves done with cur
  }

  const int b = bh >> 4, hh = bh & 15;
#pragma unroll
  for (int s = 0; s < 2; ++s) {
    float l = lrun[s];
    l += __shfl_xor(l, 16);
    l += __shfl_xor(l, 32);
    if (l != 0.f) {     // l==0 only for fully-masked row 2047 (fix blocks)
      const float rl = 1.f / l;
      float* op = out + ((size_t)(b * 2048 + qrow[s])) * 1024 + hh * 64 + quad * 4;
#pragma unroll
      for (int dt = 0; dt < 4; ++dt) {
        float4 o4;
        o4.x = acc[s][dt][0] * rl; o4.y = acc[s][dt][1] * rl;
        o4.z = acc[s][dt][2] * rl; o4.w = acc[s][dt][3] * rl;
        *reinterpret_cast<float4*>(op + dt * 16) = o4;
      }
    }
  }
}

// ---------------------------------------------------------------- launch
extern "C" void kernel_launch(void* const* d_in, const int* in_sizes, int n_in,
                              void* d_out, int out_size, void* d_ws, size_t ws_size,
                              hipStream_t stream) {
  const float* x  = (const float*)d_in[0];
  const float* Wq = (const float*)d_in[1];
  const float* bq = (const float*)d_in[2];
  const float* Wk = (const float*)d_in[3];
  const float* bk = (const float*)d_in[4];
  const float* Wv = (const float*)d_in[5];
  const float* bv = (const float*)d_in[6];
  float* out = (float*)d_out;

  char* ws = (char*)d_ws;
  u16* xb  = (u16*)(ws);                  // 8 MB: x as bf16 [4096][1024]
  u16* Wb  = (u16*)(ws + (8u << 20));     // 6 MB: Wq,Wk,Wv bf16
  u16* Qb  = (u16*)(ws + (14u << 20));    // 8 MB: Q  [B,H,S,dh] (pre-scaled)
  u16* Kb  = (u16*)(ws + (22u << 20));    // 8 MB: K  [B,H,S,dh]
  u16* VTb = (u16*)(ws + (30u << 20));    // 8 MB: V^T [B,H,dh,S]

  cvt_all<<<7168, 256, 0, stream>>>(x, Wq, Wk, Wv, xb, Wb);
  qkv_gemm<<<dim3(32, 8, 3), 256, 0, stream>>>(xb, Wb, bq, bk, bv, Qb, Kb, VTb);
  attn<<<dim3(1056), 128, 0, stream>>>(Qb, Kb, VTb, out);
}

// Round 9
// 143.392 us; speedup vs baseline: 1.0377x; 1.0377x over previous
//
#include <hip/hip_runtime.h>
#include <stdint.h>

typedef unsigned short u16;
typedef __attribute__((ext_vector_type(8))) short bf16x8;   // 8 bf16 in 4 VGPRs
typedef __attribute__((ext_vector_type(4))) float floatx4;

#define MFMA16(a, b, c) __builtin_amdgcn_mfma_f32_16x16x32_bf16(a, b, c, 0, 0, 0)
#define MEMFENCE asm volatile("" ::: "memory")

#if __has_builtin(__builtin_amdgcn_exp2f)
#define EXP2(x) __builtin_amdgcn_exp2f(x)
#else
#define EXP2(x) __expf(0.6931471805599453f * (x))
#endif

__device__ __forceinline__ u16 f2bf(float f) {   // round-to-nearest-even
  unsigned u = __builtin_bit_cast(unsigned, f);
  return (u16)((u + 0x7FFFu + ((u >> 16) & 1u)) >> 16);
}
__device__ __forceinline__ float bf2f(u16 v) {
  return __builtin_bit_cast(float, (unsigned)v << 16);
}

// pack 2 f32 -> 2 bf16 in one u32 (RNE). No builtin on gfx950 (T12): inline asm.
__device__ __forceinline__ unsigned cvtpk(float lo, float hi) {
  unsigned d;
  asm("v_cvt_pk_bf16_f32 %0, %1, %2" : "=v"(d) : "v"(lo), "v"(hi));
  return d;
}
// gfx950 half-swap primitives (VALU pipe, not DS). Both registers updated:
// P32: a=[a0,a1,b0,b1] b=[a2,a3,b2,b3]; P16: a=[a0,b0,a2,b2] b=[a1,b1,a3,b3]
// (quarters = 16-lane groups).
__device__ __forceinline__ void perm32swap(unsigned& a, unsigned& b) {
  asm("v_permlane32_swap_b32 %0, %1" : "+v"(a), "+v"(b));
}
__device__ __forceinline__ void perm16swap(unsigned& a, unsigned& b) {
  asm("v_permlane16_swap_b32 %0, %1" : "+v"(a), "+v"(b));
}

// async global->LDS, 16B/lane. LDS dest = wave-uniform base + lane*16 (HW).
__device__ __forceinline__ void glds16(void* lds, const void* g) {
  __builtin_amdgcn_global_load_lds((const __attribute__((address_space(1))) void*)g,
                                   (__attribute__((address_space(3))) void*)lds,
                                   16, 0, 0);
}

// ---------------------------------------------------------------- convert
__global__ __launch_bounds__(256) void cvt_all(
    const float* __restrict__ x, const float* __restrict__ w0,
    const float* __restrict__ w1, const float* __restrict__ w2,
    u16* __restrict__ xb, u16* __restrict__ Wb) {
  const int bid = blockIdx.x;
  const float* src;
  u16* dst;
  int i;
  if (bid < 4096) {
    src = x; dst = xb; i = bid * 256 + threadIdx.x;
  } else {
    const int z = (bid - 4096) >> 10;
    src = (z == 0) ? w0 : (z == 1) ? w1 : w2;
    dst = Wb + (size_t)z * (1024 * 1024);
    i = ((bid - 4096) & 1023) * 256 + threadIdx.x;
  }
  float4 f = reinterpret_cast<const float4*>(src)[i];
  ushort4 o;
  o.x = f2bf(f.x); o.y = f2bf(f.y); o.z = f2bf(f.z); o.w = f2bf(f.w);
  reinterpret_cast<ushort4*>(dst)[i] = o;
}

// ---------------------------------------------------------------- QKV GEMM
// (unchanged, proven) C[m,n] = sum_k x[m,k]*W[n,k] + bias[n].
__global__ __launch_bounds__(256, 3) void qkv_gemm(
    const u16* __restrict__ xb, const u16* __restrict__ Wb,
    const float* __restrict__ bq, const float* __restrict__ bk,
    const float* __restrict__ bv,
    u16* __restrict__ Qb, u16* __restrict__ Kb, u16* __restrict__ VTb) {
  __shared__ __attribute__((aligned(16))) u16 smem[2 * 128 * 64];   // 32KB
  u16* As = smem;
  u16* Bs = smem + 128 * 64;

  const int tid = threadIdx.x;
  const int w = tid >> 6, lane = tid & 63;
  const int lo = lane & 15, quad = lane >> 4;
  const int which = blockIdx.z;
  const int m0 = blockIdx.x * 128, n0 = blockIdx.y * 128;

  const u16* W = Wb + (size_t)which * (1024 * 1024);
  const int wm = (w >> 1) * 64, wn = (w & 1) * 64;

  floatx4 acc[4][4];
  for (int i = 0; i < 4; ++i)
    for (int j = 0; j < 4; ++j) acc[i][j] = (floatx4)0.f;

  const int arow = lane >> 3;                 // 0..7 within 8-row segment
  const int aswz = ((lane & 7) ^ arow) * 8;   // swizzled global col chunk

  for (int kt = 0; kt < 16; ++kt) {
    const int k0 = kt * 64;
    for (int j = 0; j < 4; ++j) {
      const int seg = w * 4 + j;              // 16 segs of 8 rows each side
      glds16(As + seg * 512, xb + (size_t)(m0 + seg * 8 + arow) * 1024 + k0 + aswz);
      glds16(Bs + seg * 512, W + (size_t)(n0 + seg * 8 + arow) * 1024 + k0 + aswz);
    }
    __syncthreads();
    for (int kk = 0; kk < 2; ++kk) {
      const int swz = ((kk * 4 + quad) ^ (lo & 7)) * 8;
      bf16x8 af[4], bfr[4];
      for (int it = 0; it < 4; ++it)
        af[it] = *reinterpret_cast<const bf16x8*>(As + (wm + it * 16 + lo) * 64 + swz);
      for (int jt = 0; jt < 4; ++jt)
        bfr[jt] = *reinterpret_cast<const bf16x8*>(Bs + (wn + jt * 16 + lo) * 64 + swz);
      for (int it = 0; it < 4; ++it)
        for (int jt = 0; jt < 4; ++jt)
          acc[it][jt] = MFMA16(af[it], bfr[jt], acc[it][jt]);
    }
    __syncthreads();
  }

  const float* bias = (which == 0) ? bq : (which == 1) ? bk : bv;
  float bb[4];
  for (int jt = 0; jt < 4; ++jt) bb[jt] = bias[n0 + wn + jt * 16 + lo];
  const int b = m0 >> 11;

  if (which < 2) {
    // per-wave 16x64 transpose tiles (pad->72, swizzled)
    const float scl = (which == 0) ? 0.36067376022224085f : 1.0f;  // 0.25*log2e
    u16* Tw = smem + w * (16 * 72);
    const int hblk = (n0 + wn) >> 6;
    u16* dst = ((which == 0) ? Qb : Kb) +
               ((size_t)(b * 16 + hblk) * 2048 + ((m0 & 2047) + wm)) * 64;
    for (int it = 0; it < 4; ++it) {
      for (int jt = 0; jt < 4; ++jt)
        for (int r = 0; r < 4; ++r) {
          const int m = quad * 4 + r, col = jt * 16 + lo;
          Tw[m * 72 + (((col >> 3) ^ (m & 7)) * 8) + (col & 7)] =
              f2bf((acc[it][jt][r] + bb[jt]) * scl);
        }
      MEMFENCE;   // scalar u16 writes -> vector reads, same wave: keep order
      for (int rd = 0; rd < 2; ++rd) {   // per-wave in-order DS: no barrier
        const int sr = rd * 8 + (lane >> 3), d8 = lane & 7;
        bf16x8 v = *reinterpret_cast<const bf16x8*>(Tw + sr * 72 + ((d8 ^ (sr & 7)) * 8));
        *reinterpret_cast<bf16x8*>(dst + (size_t)(it * 16 + sr) * 64 + d8 * 8) = v;
      }
      MEMFENCE;   // vector reads done before next it overwrites Tw
    }
  } else {
    // V^T: block transpose [128 n][64 m] (pad->72) in two m-passes.
    for (int pass = 0; pass < 2; ++pass) {
      if ((wm >> 6) == pass) {
        for (int it = 0; it < 4; ++it)
          for (int jt = 0; jt < 4; ++jt)
            for (int r = 0; r < 4; ++r) {
              const int n = wn + jt * 16 + lo;
              const int m = it * 16 + quad * 4 + r;   // local 0..63
              smem[n * 72 + (((m >> 3) ^ (n & 7)) * 8) + (m & 7)] =
                  f2bf(acc[it][jt][r] + bb[jt]);
            }
      }
      __syncthreads();
      for (int rd = 0; rd < 4; ++rd) {
        const int n = (tid >> 3) + rd * 32, m8 = tid & 7;
        bf16x8 v = *reinterpret_cast<const bf16x8*>(smem + n * 72 + ((m8 ^ (n & 7)) * 8));
        const int ng = n0 + n, h = ng >> 6, d = ng & 63;
        const int s = (m0 & 2047) + pass * 64 + m8 * 8;
        *reinterpret_cast<bf16x8*>(VTb + ((size_t)(b * 16 + h) * 64 + d) * 2048 + s) = v;
      }
      __syncthreads();
    }
  }
}

// ---------------------------------------------------------------- attention
// R9 = R6 attn VERBATIM (proven best: ~40us inferred, 16 waves/CU, 1 qset/
// wave, T12 in-register P redistribution, zero bank conflicts, ideal FETCH)
// + ONE delta: T5 s_setprio around both MFMA clusters. R8's measured 44.5us
// at 8 waves/CU vs R6's ~40 at 16 closed the shape question: wave count
// beats per-wave amortization in this latency-bound regime. T5's proven
// regime (m191, attn +4-7%) = multiple independent blocks/CU at different
// phases -- exactly this kernel (~4 blocks/CU, 4 barrier groups), unlike
// lockstep GEMM where T5 is null (m190). Pre-registered: total>146 => T5
// harmful here, revert to pure R6.
__global__ __launch_bounds__(256, 4) void attn(
    const u16* __restrict__ Qb, const u16* __restrict__ Kb,
    const u16* __restrict__ VTb, float* __restrict__ out) {
  __shared__ __attribute__((aligned(16))) u16 Ks[2][64 * 64];   // [key][d] swz
  __shared__ __attribute__((aligned(16))) u16 Vs[2][64 * 64];   // [d][key] swz

  const int L = blockIdx.x;                 // 32 fix + 1024 main
  if (L < 32) {
    // ---- fix2047: row 2047 fully masked -> uniform softmax = mean_s V ----
    const int bh = L;
    const u16* Vh = VTb + (size_t)bh * (64 * 2048);
    const int t = threadIdx.x;
    const int d = t >> 2, jj = t & 3;
    float s = 0.f;
    const u16* row = Vh + (size_t)d * 2048 + jj * 512;
    for (int i = 0; i < 64; ++i) {
      bf16x8 v = *reinterpret_cast<const bf16x8*>(row + i * 8);
      for (int e = 0; e < 8; ++e) s += bf2f((u16)v[e]);
    }
    s += __shfl_xor(s, 1);
    s += __shfl_xor(s, 2);
    if (jj == 0) {
      const int b = bh >> 4, h = bh & 15;
      out[((size_t)(b * 2048 + 2047)) * 1024 + h * 64 + d] = s * (1.f / 2048.f);
    }
    return;
  }

  const int M = L - 32;                     // 1024 main blocks
  const int bh = M & 31;                    // bh%8 = L%8 -> 4 bh per XCD (L2)
  const int j = M >> 5;                     // 0..31
  const int g = j >> 3, r = j & 7;
  const int qi = (g == 0) ? r : (g == 1) ? 15 - r : (g == 2) ? 16 + r : 31 - r;
  const int kstart = qi;                    // diagonal 64-key tile

  const int tid = threadIdx.x, w = tid >> 6, lane = tid & 63;
  const int lo = lane & 15, quad = lane >> 4;

  const u16* Qh = Qb + (size_t)bh * (2048 * 64);
  const u16* Kh = Kb + (size_t)bh * (2048 * 64);
  const u16* Vh = VTb + (size_t)bh * (64 * 2048);

  const int qrow = qi * 64 + w * 16 + lo;
  bf16x8 qf[2];
  qf[0] = *reinterpret_cast<const bf16x8*>(Qh + (size_t)qrow * 64 + quad * 8);
  qf[1] = *reinterpret_cast<const bf16x8*>(Qh + (size_t)qrow * 64 + 32 + quad * 8);

  float lrun = 0.f;
  floatx4 acc[4];
  for (int dt = 0; dt < 4; ++dt) acc[dt] = (floatx4)0.f;

  const int srow8 = lane >> 3, sblk = lane & 7;
  const int sswz = (sblk ^ srow8) * 8;          // staging XOR swizzle

  for (int jj = 0; jj < 2; ++jj) {   // prologue: stage tile kstart into buf 0
    const int b8 = (w * 2 + jj) * 8;
    glds16(&Ks[0][b8 * 64], Kh + (size_t)(kstart * 64 + b8 + srow8) * 64 + sswz);
    glds16(&Vs[0][b8 * 64], Vh + (size_t)(b8 + srow8) * 2048 + kstart * 64 + sswz);
  }
  __syncthreads();

  for (int kt = kstart; kt < 32; ++kt) {
    const int cur = (kt - kstart) & 1, nxt = cur ^ 1;
    if (kt < 31)   // prefetch next tile before compute
      for (int jj = 0; jj < 2; ++jj) {
        const int b8 = (w * 2 + jj) * 8;
        glds16(&Ks[nxt][b8 * 64], Kh + (size_t)((kt + 1) * 64 + b8 + srow8) * 64 + sswz);
        glds16(&Vs[nxt][b8 * 64], Vh + (size_t)(b8 + srow8) * 2048 + (kt + 1) * 64 + sswz);
      }
    const u16* ksb = Ks[cur];
    const u16* vsb = Vs[cur];

    const bool maskp = (kt == kstart);   // only the diagonal tile masks

    floatx4 sc[4];
    for (int t = 0; t < 4; ++t) sc[t] = (floatx4)0.f;
    __builtin_amdgcn_s_setprio(1);
#pragma unroll
    for (int kk = 0; kk < 2; ++kk) {
      const int swz = ((kk * 4 + quad) ^ (lo & 7)) * 8;
      for (int t = 0; t < 4; ++t) {
        bf16x8 ka = *reinterpret_cast<const bf16x8*>(ksb + (t * 16 + lo) * 64 + swz);
        sc[t] = MFMA16(ka, qf[kk], sc[t]);
      }
    }
    __builtin_amdgcn_s_setprio(0);

    // exp + pack: pkA[t] = [p0,p1], pkB[t] = [p2,p3] (keys t*16+quad*4+{..})
    unsigned pkA[4], pkB[4];
#pragma unroll
    for (int t = 0; t < 4; ++t) {
      float p0 = EXP2(sc[t][0]), p1 = EXP2(sc[t][1]);
      float p2 = EXP2(sc[t][2]), p3 = EXP2(sc[t][3]);
      if (maskp) {   // keep key > q (faithful buggy mask)
        const int key = kt * 64 + t * 16 + quad * 4;
        p0 = (key + 0 > qrow) ? p0 : 0.f;
        p1 = (key + 1 > qrow) ? p1 : 0.f;
        p2 = (key + 2 > qrow) ? p2 : 0.f;
        p3 = (key + 3 > qrow) ? p3 : 0.f;
      }
      lrun += (p0 + p1) + (p2 + p3);
      pkA[t] = cvtpk(p0, p1);
      pkB[t] = cvtpk(p2, p3);
    }

    // in-register P redistribution + PV (no LDS, no fences)
#pragma unroll
    for (int kk = 0; kk < 2; ++kk) {
      unsigned a0 = pkA[2 * kk], a1 = pkA[2 * kk + 1];
      unsigned b0 = pkB[2 * kk], b1 = pkB[2 * kk + 1];
      perm32swap(a0, a1); perm16swap(a0, a1);   // a0=PB0, a1=PB2
      perm32swap(b0, b1); perm16swap(b0, b1);   // b0=PB1, b1=PB3
      uint4 pw; pw.x = a0; pw.y = b0; pw.z = a1; pw.w = b1;
      const bf16x8 pb = __builtin_bit_cast(bf16x8, pw);
      const int pswz = ((kk * 4 + quad) ^ (lo & 7)) * 8;
      __builtin_amdgcn_s_setprio(1);
      for (int dt = 0; dt < 4; ++dt) {
        bf16x8 va = *reinterpret_cast<const bf16x8*>(vsb + (dt * 16 + lo) * 64 + pswz);
        acc[dt] = MFMA16(va, pb, acc[dt]);
      }
      __builtin_amdgcn_s_setprio(0);
    }
    __syncthreads();   // staging of nxt complete + all waves done with cur
  }

  const int b = bh >> 4, hh = bh & 15;
  float l = lrun;
  l += __shfl_xor(l, 16);
  l += __shfl_xor(l, 32);
  if (l != 0.f) {     // l==0 only for fully-masked row 2047 (fix blocks)
    const float rl = 1.f / l;
    float* op = out + ((size_t)(b * 2048 + qrow)) * 1024 + hh * 64 + quad * 4;
    for (int dt = 0; dt < 4; ++dt) {
      float4 o4;
      o4.x = acc[dt][0] * rl; o4.y = acc[dt][1] * rl;
      o4.z = acc[dt][2] * rl; o4.w = acc[dt][3] * rl;
      *reinterpret_cast<float4*>(op + dt * 16) = o4;
    }
  }
}

// ---------------------------------------------------------------- launch
extern "C" void kernel_launch(void* const* d_in, const int* in_sizes, int n_in,
                              void* d_out, int out_size, void* d_ws, size_t ws_size,
                              hipStream_t stream) {
  const float* x  = (const float*)d_in[0];
  const float* Wq = (const float*)d_in[1];
  const float* bq = (const float*)d_in[2];
  const float* Wk = (const float*)d_in[3];
  const float* bk = (const float*)d_in[4];
  const float* Wv = (const float*)d_in[5];
  const float* bv = (const float*)d_in[6];
  float* out = (float*)d_out;

  char* ws = (char*)d_ws;
  u16* xb  = (u16*)(ws);                  // 8 MB: x as bf16 [4096][1024]
  u16* Wb  = (u16*)(ws + (8u << 20));     // 6 MB: Wq,Wk,Wv bf16
  u16* Qb  = (u16*)(ws + (14u << 20));    // 8 MB: Q  [B,H,S,dh] (pre-scaled)
  u16* Kb  = (u16*)(ws + (22u << 20));    // 8 MB: K  [B,H,S,dh]
  u16* VTb = (u16*)(ws + (30u << 20));    // 8 MB: V^T [B,H,dh,S]

  cvt_all<<<7168, 256, 0, stream>>>(x, Wq, Wk, Wv, xb, Wb);
  qkv_gemm<<<dim3(32, 8, 3), 256, 0, stream>>>(xb, Wb, bq, bk, bv, Qb, Kb, VTb);
  attn<<<dim3(1056), 256, 0, stream>>>(Qb, Kb, VTb, out);
}